// Round 1
// baseline (656.846 us; speedup 1.0000x reference)
//
#include <hip/hip_runtime.h>

// New_msa fused implementation for MI355X (gfx950).
// B=4, H=W=256, C=128, heads=4, d=32, gabor scales=4, ks=7.
//
// Math restructuring:
//  - S_b = x_bT x_b (per-batch 128x128) => attention Gram + q/k norms without
//    materializing q/k:  G[d,e] = Wk_d^T S Wq_e,  ||q_e||^2 = Wq_e^T S Wq_e.
//  - out_c = v @ W2_b + bproj with W2_b[he,co] = sum_d attn[h,d,e] Wproj[hd,co].
//  - gabor kernel separable: k[s,i,j] = a[i]*b_s[j]; a,b extracted from dw_w.
//  - final kernel: per 8x8 pixel tile, GEMM [64 x 640]x[640 x 128] bf16 MFMA,
//    g (512ch) built on the fly in LDS (never hits HBM).
//
// ws layout (bytes):            size
//   v bf16   [4][65536][128]    67,108,864   @ 0
//   partialS [512][128][128]f32 33,554,432   @ 67,108,864
//   S        [4][128][128] f32     262,144   @ 100,663,296
//   W2T bf16 [4][128][128]         131,072   @ 100,925,440
//   pw bf16  [128][512]            131,072   @ 101,056,512
// total 101,187,584 B (needs ws_size >= ~96.5 MiB)

using bf16x8 = __attribute__((ext_vector_type(8))) short;
using f32x4  = __attribute__((ext_vector_type(4))) float;

__device__ __forceinline__ unsigned short f2bf(float f) {
  union { float f; unsigned u; } v; v.f = f;
  unsigned r = v.u + 0x7FFFu + ((v.u >> 16) & 1u);   // RNE
  return (unsigned short)(r >> 16);
}
__device__ __forceinline__ float bf2f(unsigned short u) {
  union { unsigned u; float f; } v; v.u = ((unsigned)u) << 16;
  return v.f;
}
__device__ __forceinline__ float gelu_f(float x) {
  // tanh-form GELU (|err| <= ~3e-3 vs exact erf form; threshold is 0.116)
  float u = 0.7978845608028654f * (x + 0.044715f * x * x * x);
  float e = __expf(2.0f * u);
  float th = 1.0f - 2.0f / (e + 1.0f);   // robust tanh (inf-safe)
  return 0.5f * x * (1.0f + th);
}

// ---------------- K0: pw_w fp32 -> bf16 (layout unchanged: [o][ch]) ---------
__global__ void k_prep(const float* __restrict__ pw, unsigned short* __restrict__ pwb) {
  int idx = blockIdx.x * 256 + threadIdx.x;   // 65536 total
  pwb[idx] = f2bf(pw[idx]);
}

// ---------------- K1: fused v = x@Wv  and  partial S = x^T x ----------------
// grid 512 (= 4 batches * 128 chunks of 512 rows), 256 threads.
__global__ __launch_bounds__(256, 2) void k_vgram(
    const float* __restrict__ x, const float* __restrict__ Wv,
    unsigned short* __restrict__ vout, float* __restrict__ partial) {
  __shared__ unsigned short WvT[128][136];  // [c_out][c_in], pitch-padded
  __shared__ unsigned short xs[64][136];    // [row][c_in]
  const int tid = threadIdx.x;
  const int bid = blockIdx.x;
  const int b = bid >> 7;
  const long n0 = (long)(bid & 127) * 512;
  const float* __restrict__ xb = x + (long)b * 65536 * 128;

  { // stage Wv transposed -> bf16 (one-time per block; Wv is L2-hot)
    int c = tid >> 1;
    int o0 = (tid & 1) * 64;
    const float* src = Wv + c * 128 + o0;
    #pragma unroll
    for (int u = 0; u < 64; u += 4) {
      float4 w = *(const float4*)(src + u);
      WvT[o0 + u + 0][c] = f2bf(w.x);
      WvT[o0 + u + 1][c] = f2bf(w.y);
      WvT[o0 + u + 2][c] = f2bf(w.z);
      WvT[o0 + u + 3][c] = f2bf(w.w);
    }
  }
  __syncthreads();

  const int wave = tid >> 6, lane = tid & 63;
  const int quad = lane >> 4, l16 = lane & 15;

  f32x4 accg[2][8];   // Gram accumulators: m-tiles {2w,2w+1} x 8 n-tiles
  #pragma unroll
  for (int i = 0; i < 2; ++i)
    #pragma unroll
    for (int nt = 0; nt < 8; ++nt) accg[i][nt] = (f32x4){0.f, 0.f, 0.f, 0.f};

  for (int so = 0; so < 8; ++so) {
    const long r0 = n0 + so * 64;
    { // stage 64 rows of x -> bf16 LDS
      int row = tid >> 2;
      int c0 = (tid & 3) * 32;
      const float* src = xb + (r0 + row) * 128 + c0;
      #pragma unroll
      for (int u = 0; u < 32; u += 4) {
        float4 t = *(const float4*)(src + u);
        ushort4 p;
        p.x = f2bf(t.x); p.y = f2bf(t.y); p.z = f2bf(t.z); p.w = f2bf(t.w);
        *(ushort4*)&xs[row][c0 + u] = p;
      }
    }
    __syncthreads();

    // ---- v-GEMM: D[row, c_out] = x-tile @ Wv ----
    f32x4 accv[8];
    #pragma unroll
    for (int nt = 0; nt < 8; ++nt) accv[nt] = (f32x4){0.f, 0.f, 0.f, 0.f};
    #pragma unroll
    for (int ks = 0; ks < 4; ++ks) {
      bf16x8 af = *(const bf16x8*)&xs[16 * wave + l16][32 * ks + 8 * quad];
      #pragma unroll
      for (int nt = 0; nt < 8; ++nt) {
        bf16x8 bfr = *(const bf16x8*)&WvT[16 * nt + l16][32 * ks + 8 * quad];
        accv[nt] = __builtin_amdgcn_mfma_f32_16x16x32_bf16(af, bfr, accv[nt], 0, 0, 0);
      }
    }
    { // store v (bf16). C/D layout: row = 4*quad+r, col = l16  [m89]
      long rbase = (long)b * 65536 + r0 + 16 * wave + 4 * quad;
      #pragma unroll
      for (int nt = 0; nt < 8; ++nt)
        #pragma unroll
        for (int r = 0; r < 4; ++r)
          vout[(rbase + r) * 128 + 16 * nt + l16] = f2bf(accv[nt][r]);
    }

    // ---- Gram: S += x_tile^T x_tile. A-frag and B-frag of tile t are the
    // SAME registers (both hold x[k=row][16t+l16]), loaded straight from
    // global (L1/L2-hot: this tile was just staged). ----
    #pragma unroll
    for (int ks = 0; ks < 2; ++ks) {
      bf16x8 fr[8];
      bf16x8 fa0, fa1;
      const long kr0 = r0 + 32 * ks + 8 * quad;
      #pragma unroll
      for (int t8 = 0; t8 < 8; ++t8) {
        const float* p = xb + kr0 * 128 + 16 * t8 + l16;
        bf16x8 f;
        #pragma unroll
        for (int j = 0; j < 8; ++j) f[j] = (short)f2bf(p[j * 128]);
        fr[t8] = f;
        if (t8 == 2 * wave)     fa0 = f;   // avoid dynamic reg-array index
        if (t8 == 2 * wave + 1) fa1 = f;
      }
      #pragma unroll
      for (int nt = 0; nt < 8; ++nt) {
        accg[0][nt] = __builtin_amdgcn_mfma_f32_16x16x32_bf16(fa0, fr[nt], accg[0][nt], 0, 0, 0);
        accg[1][nt] = __builtin_amdgcn_mfma_f32_16x16x32_bf16(fa1, fr[nt], accg[1][nt], 0, 0, 0);
      }
    }
    __syncthreads();
  }

  { // per-block partial S (no atomics; reduced by k_reduce)
    float* pp = partial + (long)bid * 16384;
    #pragma unroll
    for (int i = 0; i < 2; ++i) {
      int mr = 16 * (2 * wave + i) + 4 * quad;
      #pragma unroll
      for (int nt = 0; nt < 8; ++nt)
        #pragma unroll
        for (int r = 0; r < 4; ++r)
          pp[(mr + r) * 128 + 16 * nt + l16] = accg[i][nt][r];
    }
  }
}

// ---------------- K1c: reduce 128 partials per batch -> S -------------------
__global__ void k_reduce(const float* __restrict__ partial, float* __restrict__ S) {
  int idx = blockIdx.x * 256 + threadIdx.x;   // 65536 = 4*128*128
  int bb = idx >> 14;
  int ij = idx & 16383;
  const float* p = partial + (long)bb * 128 * 16384 + ij;
  float s = 0.f;
  for (int k = 0; k < 128; ++k) s += p[(long)k * 16384];
  S[idx] = s;
}

// ---------------- K2: Gram -> softmax attn -> W2T (per b,h) -----------------
__global__ void k_attn(const float* __restrict__ S, const float* __restrict__ Wq,
                       const float* __restrict__ Wk, const float* __restrict__ rescale,
                       const float* __restrict__ Wproj, unsigned short* __restrict__ W2T) {
  __shared__ float Tq[128][33];
  __shared__ float Tk[128][33];
  __shared__ float G[32][33];
  __shared__ float attnS[32][33];
  __shared__ float nq[32], nk[32];
  const int tid = threadIdx.x;
  const int b = blockIdx.x >> 2;
  const int h = blockIdx.x & 3;
  const float* Sb = S + b * 16384;

  { // Tq = S*Wq_h, Tk = S*Wk_h  (columns 32h..32h+31)
    int e = tid & 31;
    int i0 = (tid >> 5) * 16;
    int col = 32 * h + e;
    float aq[16], ak[16];
    #pragma unroll
    for (int i = 0; i < 16; ++i) { aq[i] = 0.f; ak[i] = 0.f; }
    for (int j = 0; j < 128; ++j) {
      float wq = Wq[j * 128 + col];
      float wk = Wk[j * 128 + col];
      const float* srow = Sb + i0 * 128 + j;
      #pragma unroll
      for (int i = 0; i < 16; ++i) {
        float s = srow[i * 128];
        aq[i] += s * wq;
        ak[i] += s * wk;
      }
    }
    #pragma unroll
    for (int i = 0; i < 16; ++i) { Tq[i0 + i][e] = aq[i]; Tk[i0 + i][e] = ak[i]; }
  }
  __syncthreads();
  { // G[d][e] = Wk_d . Tq[:,e]
    int e = tid & 31;
    int d0 = (tid >> 5) * 4;
    float g[4] = {0.f, 0.f, 0.f, 0.f};
    for (int i = 0; i < 128; ++i) {
      float tq = Tq[i][e];
      #pragma unroll
      for (int d = 0; d < 4; ++d) g[d] += Wk[i * 128 + 32 * h + d0 + d] * tq;
    }
    #pragma unroll
    for (int d = 0; d < 4; ++d) G[d0 + d][e] = g[d];
  }
  if (tid < 32) {          // ||q_e||^2
    float s = 0.f;
    for (int i = 0; i < 128; ++i) s += Wq[i * 128 + 32 * h + tid] * Tq[i][tid];
    nq[tid] = s;
  } else if (tid < 64) {   // ||k_d||^2
    int d = tid - 32;
    float s = 0.f;
    for (int i = 0; i < 128; ++i) s += Wk[i * 128 + 32 * h + d] * Tk[i][d];
    nk[d] = s;
  }
  __syncthreads();
  if (tid < 32) {          // softmax over e per row d
    int d = tid;
    float rsc = rescale[h];
    float rk = fmaxf(sqrtf(fmaxf(nk[d], 0.f)), 1e-12f);
    float L[32];
    float mx = -3.4e38f;
    #pragma unroll
    for (int e = 0; e < 32; ++e) {
      float rq = fmaxf(sqrtf(fmaxf(nq[e], 0.f)), 1e-12f);
      float l = G[d][e] * rsc / (rk * rq);
      L[e] = l;
      mx = fmaxf(mx, l);
    }
    float sum = 0.f;
    #pragma unroll
    for (int e = 0; e < 32; ++e) {
      float p = __expf(L[e] - mx);
      attnS[d][e] = p;
      sum += p;
    }
    float inv = 1.0f / sum;
    #pragma unroll
    for (int e = 0; e < 32; ++e) attnS[d][e] *= inv;
  }
  __syncthreads();
  { // W2T[b][co][32h+e] = sum_d attn[d][e] * Wproj[32h+d][co]   (bf16)
    int co = tid & 127;
    int e0 = (tid >> 7) * 16;
    float s[16];
    #pragma unroll
    for (int e = 0; e < 16; ++e) s[e] = 0.f;
    for (int d = 0; d < 32; ++d) {
      float wp = Wproj[(32 * h + d) * 128 + co];
      #pragma unroll
      for (int e = 0; e < 16; ++e) s[e] += attnS[d][e0 + e] * wp;
    }
    #pragma unroll
    for (int e = 0; e < 16; ++e)
      W2T[((long)b * 128 + co) * 128 + 32 * h + e0 + e] = f2bf(s[e]);
  }
}

// ---------------- K3: fused gabor + dual GEMM + bias -> out -----------------
// grid 4096 = 4 batches * 32*32 tiles of 8x8 pixels; 256 threads.
__global__ __launch_bounds__(256, 2) void k_final(
    const unsigned short* __restrict__ v, const unsigned short* __restrict__ W2T,
    const unsigned short* __restrict__ pwb, const float* __restrict__ dw_w,
    const float* __restrict__ dw_b, const float* __restrict__ bproj,
    const float* __restrict__ pw_b, float* __restrict__ out) {
  __shared__ unsigned short t_lds[8 * 14 * 132];  // vertical-conv tile [yl][xh][c]
  __shared__ unsigned short A_lds[64 * 72];       // [pix][k-chunk 64]
  __shared__ unsigned short B_lds[128 * 72];      // [o][k-chunk 64]
  const int tid = threadIdx.x;
  const int bid = blockIdx.x;
  const int b = bid >> 10;
  const int tile = bid & 1023;
  const int y0 = (tile >> 5) * 8;
  const int x0 = (tile & 31) * 8;

  // separable gabor weights from dw_w: a[i]=w[0][i][4], b_s[j]=w[s][4][j]
  float a_[7];
  #pragma unroll
  for (int i = 0; i < 7; ++i) a_[i] = dw_w[i * 7 + 4];
  float bco[4][7];
  #pragma unroll
  for (int s = 0; s < 4; ++s)
    #pragma unroll
    for (int j = 0; j < 7; ++j) bco[s][j] = dw_w[s * 49 + 28 + j];

  // ---- vertical 7-tap pass: t[yl][xh][c], xh covers x0-3..x0+10 ----
  #pragma unroll
  for (int it = 0; it < 2; ++it) {
    int colid = tid + 256 * it;
    if (colid < 448) {                 // 14 xh * 32 c-quads
      int xh = colid >> 5;
      int c4 = (colid & 31) * 4;
      int xg = x0 + xh - 3;
      bool inx = (xg >= 0) && (xg < 256);
      float rows_[14][4];
      #pragma unroll
      for (int yy = 0; yy < 14; ++yy) {
        int yg = y0 + yy - 3;
        float f0 = 0.f, f1 = 0.f, f2 = 0.f, f3 = 0.f;
        if (inx && yg >= 0 && yg < 256) {
          ushort4 vv = *(const ushort4*)&v[((long)b * 65536 + yg * 256 + xg) * 128 + c4];
          f0 = bf2f(vv.x); f1 = bf2f(vv.y); f2 = bf2f(vv.z); f3 = bf2f(vv.w);
        }
        rows_[yy][0] = f0; rows_[yy][1] = f1; rows_[yy][2] = f2; rows_[yy][3] = f3;
      }
      #pragma unroll
      for (int yl = 0; yl < 8; ++yl) {
        float t0 = 0.f, t1 = 0.f, t2 = 0.f, t3 = 0.f;
        #pragma unroll
        for (int i = 0; i < 7; ++i) {
          float w = a_[i];
          t0 += w * rows_[yl + i][0];
          t1 += w * rows_[yl + i][1];
          t2 += w * rows_[yl + i][2];
          t3 += w * rows_[yl + i][3];
        }
        ushort4 p; p.x = f2bf(t0); p.y = f2bf(t1); p.z = f2bf(t2); p.w = f2bf(t3);
        *(ushort4*)&t_lds[(yl * 14 + xh) * 132 + c4] = p;
      }
    }
  }
  __syncthreads();

  const int wave = tid >> 6, lane = tid & 63;
  const int quad = lane >> 4, l16 = lane & 15;
  f32x4 acc[8];
  #pragma unroll
  for (int nt = 0; nt < 8; ++nt) acc[nt] = (f32x4){0.f, 0.f, 0.f, 0.f};

  // K = 640 in 10 chunks of 64: kc 0..1 = v@W2 (attention), kc 2..9 = gabor@pw
  for (int kc = 0; kc < 10; ++kc) {
    { // stage B chunk: BT[o][k]
      int o = tid >> 1;
      int k0 = (tid & 1) * 32;
      const unsigned short* src = (kc < 2)
          ? (W2T + ((long)b * 128 + o) * 128 + kc * 64 + k0)
          : (pwb + (long)o * 512 + (kc - 2) * 64 + k0);
      #pragma unroll
      for (int u = 0; u < 32; u += 8)
        *(uint4*)&B_lds[o * 72 + k0 + u] = *(const uint4*)(src + u);
    }
    if (kc < 2) { // A chunk = v tile
      int pix = tid >> 2;
      int c0 = (tid & 3) * 16;
      const unsigned short* src =
          v + ((long)b * 65536 + (y0 + (pix >> 3)) * 256 + x0 + (pix & 7)) * 128 + kc * 64 + c0;
      *(uint4*)&A_lds[pix * 72 + c0]     = *(const uint4*)(src);
      *(uint4*)&A_lds[pix * 72 + c0 + 8] = *(const uint4*)(src + 8);
    } else {      // A chunk = GELU(horizontal 7-tap of t) for c in [16kcg,16kcg+16)
      int kcg = kc - 2;
      int pix = tid >> 2;
      int cl = (tid & 3) * 4;
      int yl = pix >> 3, xl = pix & 7;
      float tv[7][4];
      #pragma unroll
      for (int j = 0; j < 7; ++j) {
        ushort4 tt = *(const ushort4*)&t_lds[(yl * 14 + xl + j) * 132 + 16 * kcg + cl];
        tv[j][0] = bf2f(tt.x); tv[j][1] = bf2f(tt.y); tv[j][2] = bf2f(tt.z); tv[j][3] = bf2f(tt.w);
      }
      #pragma unroll
      for (int cc = 0; cc < 4; ++cc) {
        int ch = (16 * kcg + cl + cc) * 4;    // g-channel base = 4*c
        unsigned short gs[4];
        #pragma unroll
        for (int s = 0; s < 4; ++s) {
          float g = dw_b[ch + s];
          #pragma unroll
          for (int j = 0; j < 7; ++j) g += bco[s][j] * tv[j][cc];
          gs[s] = f2bf(gelu_f(g));
        }
        ushort4 p; p.x = gs[0]; p.y = gs[1]; p.z = gs[2]; p.w = gs[3];
        *(ushort4*)&A_lds[pix * 72 + 4 * (cl + cc)] = p;   // k-local = 4*c_local+s
      }
    }
    __syncthreads();
    #pragma unroll
    for (int ks = 0; ks < 2; ++ks) {
      bf16x8 af = *(const bf16x8*)&A_lds[(16 * wave + l16) * 72 + 32 * ks + 8 * quad];
      #pragma unroll
      for (int nt = 0; nt < 8; ++nt) {
        bf16x8 bfr = *(const bf16x8*)&B_lds[(16 * nt + l16) * 72 + 32 * ks + 8 * quad];
        acc[nt] = __builtin_amdgcn_mfma_f32_16x16x32_bf16(af, bfr, acc[nt], 0, 0, 0);
      }
    }
    __syncthreads();
  }

  // epilogue: + bproj + pw_b, fp32 store
  int mr = 16 * wave + 4 * quad;
  #pragma unroll
  for (int nt = 0; nt < 8; ++nt) {
    int col = 16 * nt + l16;
    float bias = bproj[col] + pw_b[col];
    #pragma unroll
    for (int r = 0; r < 4; ++r) {
      int pix = mr + r;
      out[((long)b * 65536 + (y0 + (pix >> 3)) * 256 + x0 + (pix & 7)) * 128 + col] =
          acc[nt][r] + bias;
    }
  }
}

extern "C" void kernel_launch(void* const* d_in, const int* in_sizes, int n_in,
                              void* d_out, int out_size, void* d_ws, size_t ws_size,
                              hipStream_t stream) {
  const float* x       = (const float*)d_in[0];
  const float* Wq      = (const float*)d_in[1];
  const float* Wk      = (const float*)d_in[2];
  const float* Wv      = (const float*)d_in[3];
  const float* rescale = (const float*)d_in[4];
  const float* Wproj   = (const float*)d_in[5];
  const float* bproj   = (const float*)d_in[6];
  const float* dw_w    = (const float*)d_in[7];
  const float* dw_b    = (const float*)d_in[8];
  const float* pw_w    = (const float*)d_in[9];
  const float* pw_b    = (const float*)d_in[10];
  float* out = (float*)d_out;

  char* ws = (char*)d_ws;
  unsigned short* v       = (unsigned short*)(ws);
  float*          partial = (float*)(ws + 67108864);
  float*          S       = (float*)(ws + 100663296);
  unsigned short* W2T     = (unsigned short*)(ws + 100925440);
  unsigned short* pwb     = (unsigned short*)(ws + 101056512);

  k_prep  <<<256, 256, 0, stream>>>(pw_w, pwb);
  k_vgram <<<512, 256, 0, stream>>>(x, Wv, v, partial);
  k_reduce<<<256, 256, 0, stream>>>(partial, S);
  k_attn  <<<16,  256, 0, stream>>>(S, Wq, Wk, rescale, Wproj, W2T);
  k_final <<<4096,256, 0, stream>>>(v, W2T, pwb, dw_w, dw_b, bproj, pw_b, out);
}